// Round 13
// baseline (229.320 us; speedup 1.0000x reference)
//
#include <hip/hip_runtime.h>
#include <math.h>
#include <stdint.h>

#define S_LEN 1024
#define D_DIM 64
#define BH    32
#define KSHIFT 13
#define NBINS 130048u             // 0x3F800000 >> 13 : |score| < 1.0, 18-bit keys
#define HOT_LO 115712u            // pv LDS table: |s| >= 2^-14
#define NHOT   14336u             // pv table bins
#define HIST_LO 117760u           // hist LDS range: |s| >= 2^-12
#define NHOT_H  12288u            // hist hot bins
#define NCHUNK 254                // NBINS / 512
#define QHB    512                // qkhist blocks
#define INV_NM1 (1.0f/33554431.0f)
#define INV_N   (2.9802322387695312e-08f)  // 1/2^25
#define FIX_TH  1e-4f             // |s| below this -> wave-coop fp64 recompute (~21K elems)

typedef _Float16 half8 __attribute__((ext_vector_type(8)));
typedef short    short8 __attribute__((ext_vector_type(8)));
typedef float    floatx4 __attribute__((ext_vector_type(4)));

// ---------------- row norms: 1/(||row||+1e-5), fp64 + fp32 copies ----------------
__global__ __launch_bounds__(256) void norms_kernel(
    const float* __restrict__ Q, const float* __restrict__ K,
    double* __restrict__ qinvD, double* __restrict__ kinvD,
    float* __restrict__ qinvF, float* __restrict__ kinvF) {
  int row  = blockIdx.x * 4 + (threadIdx.x >> 6);
  int lane = threadIdx.x & 63;
  const float* src; double* dstD; float* dstF; int r = row;
  if (row < BH * S_LEN) { src = Q; dstD = qinvD; dstF = qinvF; }
  else                  { src = K; dstD = kinvD; dstF = kinvF; r = row - BH * S_LEN; }
  double v = (double)src[(size_t)r * D_DIM + lane];
  double s = v * v;
  #pragma unroll
  for (int off = 32; off; off >>= 1) s += __shfl_down(s, off);
  if (lane == 0) {
    double inv = 1.0 / (sqrt(s) + 1e-5);
    dstD[r] = inv;
    dstF[r] = (float)inv;
  }
}

// bf16 split helper: x -> hi (RNE) + lo (RZ of residual), as raw bf16 bit patterns
__device__ __forceinline__ void bf16_split(float x, short& hi, short& lo) {
  unsigned u = __float_as_uint(x);
  unsigned h = (u + 0x7FFFu + ((u >> 16) & 1u)) >> 16;   // RNE to bf16
  float hf = __uint_as_float(h << 16);
  float lf = x - hf;                                     // exact (Sterbenz)
  hi = (short)h;
  lo = (short)(__float_as_uint(lf) >> 16);               // RZ to bf16
}

// ------- fused QK^T (bf16-split MFMA) + fp64 fixup + score write + LDS histogram -------
// Block: 512 thr = 8 waves = 4 row-groups x 2 nt-halves; one 64-row i-stripe x 16 j-tiles.
__global__ __launch_bounds__(512, 4) void qkhist_kernel(
    const float* __restrict__ Q, const float* __restrict__ K,
    const float* __restrict__ qinvF, const float* __restrict__ kinvF,
    const double* __restrict__ qinvD, const double* __restrict__ kinvD,
    float* __restrict__ score, unsigned* __restrict__ hist,
    unsigned char* __restrict__ partial) {
  __shared__ short Qhi[64][72], Qlo[64][72];     // 18,432 B
  __shared__ short Khi[64][72], Klo[64][72];     // 18,432 B
  __shared__ unsigned lh[NHOT_H / 2];            // 24,576 B: two u16 bins per u32
  int tid = threadIdx.x;
  int bh  = blockIdx.x >> 4;
  int i0  = (blockIdx.x & 15) * 64;
  for (unsigned i = tid; i < NHOT_H / 2; i += 512) lh[i] = 0u;
  // stage Q once per block
  const float* Qb = Q + ((size_t)bh * S_LEN + i0) * D_DIM;
  #pragma unroll
  for (int l = 0; l < 2; ++l) {
    int idx4 = l * 512 + tid;          // 0..1023 float4 of 64x64 tile
    int row  = idx4 >> 4;
    int c4   = idx4 & 15;
    float qi = qinvF[(size_t)bh * S_LEN + i0 + row];
    float4 v = ((const float4*)Qb)[idx4];
    float qv[4] = {v.x * qi, v.y * qi, v.z * qi, v.w * qi};
    short qh[4], ql[4];
    #pragma unroll
    for (int c = 0; c < 4; ++c) bf16_split(qv[c], qh[c], ql[c]);
    *(short4*)&Qhi[row][c4 * 4] = make_short4(qh[0], qh[1], qh[2], qh[3]);
    *(short4*)&Qlo[row][c4 * 4] = make_short4(ql[0], ql[1], ql[2], ql[3]);
  }
  int wave = tid >> 6;
  int lane = tid & 63;
  int m    = lane & 15;
  int quad = lane >> 4;
  int g    = wave >> 1;     // row group 0..3
  int h    = wave & 1;      // nt-half 0..1

  for (int jt = 0; jt < 16; ++jt) {
    int j0 = jt * 64;
    __syncthreads();   // prev tile's K ds_reads done (1st iter: lh zero + Q staged)
    const float* Kb = K + ((size_t)bh * S_LEN + j0) * D_DIM;
    #pragma unroll
    for (int l = 0; l < 2; ++l) {
      int idx4 = l * 512 + tid;
      int row  = idx4 >> 4;
      int c4   = idx4 & 15;
      float kj = kinvF[(size_t)bh * S_LEN + j0 + row];
      float4 w = ((const float4*)Kb)[idx4];
      float kv[4] = {w.x * kj, w.y * kj, w.z * kj, w.w * kj};
      short kh[4], kl[4];
      #pragma unroll
      for (int c = 0; c < 4; ++c) bf16_split(kv[c], kh[c], kl[c]);
      *(short4*)&Khi[row][c4 * 4] = make_short4(kh[0], kh[1], kh[2], kh[3]);
      *(short4*)&Klo[row][c4 * 4] = make_short4(kl[0], kl[1], kl[2], kl[3]);
    }
    __syncthreads();
    floatx4 acc[2];
    acc[0] = (floatx4){0.f, 0.f, 0.f, 0.f};
    acc[1] = (floatx4){0.f, 0.f, 0.f, 0.f};
    #pragma unroll
    for (int ks = 0; ks < 2; ++ks) {
      int kb = ks * 32 + quad * 8;
      short8 a_hi = *(const short8*)&Qhi[g * 16 + m][kb];
      short8 a_lo = *(const short8*)&Qlo[g * 16 + m][kb];
      #pragma unroll
      for (int t = 0; t < 2; ++t) {
        int nt = h * 2 + t;
        short8 b_hi = *(const short8*)&Khi[nt * 16 + m][kb];
        short8 b_lo = *(const short8*)&Klo[nt * 16 + m][kb];
        acc[t] = __builtin_amdgcn_mfma_f32_16x16x32_bf16(a_hi, b_hi, acc[t], 0, 0, 0);
        acc[t] = __builtin_amdgcn_mfma_f32_16x16x32_bf16(a_hi, b_lo, acc[t], 0, 0, 0);
        acc[t] = __builtin_amdgcn_mfma_f32_16x16x32_bf16(a_lo, b_hi, acc[t], 0, 0, 0);
      }
    }
    float sv[8];
    #pragma unroll
    for (int t = 0; t < 2; ++t)
      #pragma unroll
      for (int r = 0; r < 4; ++r) sv[t * 4 + r] = acc[t][r];

    // ---- rare fp64 fixup (wave-cooperative, no global atomics) ----
    bool anyf = false;
    #pragma unroll
    for (int e = 0; e < 8; ++e) anyf |= (fabsf(sv[e]) < FIX_TH);
    unsigned long long am = __ballot(anyf);
    while (am) {
      int src = (int)(__ffsll((long long)am) - 1);
      am &= am - 1;
      #pragma unroll
      for (int e = 0; e < 8; ++e) {
        float sc = __shfl(sv[e], src);
        if (fabsf(sc) < FIX_TH) {
          int t = e >> 2, r = e & 3;
          int row = i0 + g * 16 + ((src >> 4)) * 4 + r;
          int col = j0 + (h * 2 + t) * 16 + (src & 15);
          double qd = (double)Q[((size_t)bh * S_LEN + row) * D_DIM + lane];
          double kd = (double)K[((size_t)bh * S_LEN + col) * D_DIM + lane];
          double pd = qd * kd;
          #pragma unroll
          for (int off = 32; off; off >>= 1) pd += __shfl_down(pd, off);
          float corr = 0.f;
          if (lane == 0)
            corr = (float)(pd * qinvD[(size_t)bh * S_LEN + row] * kinvD[(size_t)bh * S_LEN + col]);
          corr = __shfl(corr, 0);
          if (lane == src) sv[e] = corr;
        }
      }
    }
    // ---- score write (C/D layout: row = quad*4+r, col = m) ----
    #pragma unroll
    for (int r = 0; r < 4; ++r) {
      float* op = score + ((size_t)bh * S_LEN + i0 + g * 16 + quad * 4 + r) * S_LEN + j0 + m;
      op[(h * 2 + 0) * 16] = sv[r];
      op[(h * 2 + 1) * 16] = sv[4 + r];
    }
    // ---- binning: hot -> packed LDS (halves can't overflow: max count ~128) ----
    #pragma unroll
    for (int e = 0; e < 8; ++e) {
      unsigned b = __float_as_uint(fabsf(sv[e])) >> KSHIFT;
      if (b >= NBINS) b = NBINS - 1u;
      if (b >= HIST_LO) {
        unsigned bb = b - HIST_LO;
        atomicAdd(&lh[bb >> 1], (bb & 1u) ? 65536u : 1u);
      } else {
        atomicAdd(&hist[b], 1u);   // rare (~1.6e-3 of values)
      }
    }
  }
  __syncthreads();
  unsigned char* dst = partial + (size_t)blockIdx.x * NHOT_H;
  for (unsigned i = tid; i < NHOT_H / 2; i += 512) {
    unsigned w = lh[i];
    dst[2 * i]     = (unsigned char)(w & 0xffffu);
    dst[2 * i + 1] = (unsigned char)(w >> 16);
  }
}

// ---------------- reduce u8 partial histograms into hist hot range ----------------
__global__ __launch_bounds__(256) void hreduce_kernel(
    const unsigned char* __restrict__ partial, unsigned* __restrict__ hist) {
  unsigned bin = blockIdx.x * 256 + threadIdx.x;   // 48 blocks * 256 = 12288
  unsigned s = 0;
  #pragma unroll 8
  for (int b = 0; b < QHB; ++b) s += (unsigned)partial[(size_t)b * NHOT_H + bin];
  hist[HIST_LO + bin] = s;
}

// ---------------- V (fp32 [j][d]) -> Vt (fp16 [d][j]) ----------------
__global__ __launch_bounds__(256) void vt_kernel(
    const float* __restrict__ V, _Float16* __restrict__ Vt) {
  __shared__ _Float16 T[64][72];
  int bh = blockIdx.y, j0 = blockIdx.x * 64, tid = threadIdx.x;
  const float* Vb = V + ((size_t)bh * S_LEN + j0) * D_DIM;
  #pragma unroll
  for (int l = 0; l < 4; ++l) {
    int idx = l * 256 + tid;
    int jr = idx >> 4, d4 = idx & 15;
    float4 v = ((const float4*)Vb)[idx];
    T[d4*4+0][jr] = (_Float16)v.x;
    T[d4*4+1][jr] = (_Float16)v.y;
    T[d4*4+2][jr] = (_Float16)v.z;
    T[d4*4+3][jr] = (_Float16)v.w;
  }
  __syncthreads();
  _Float16* Ob = Vt + (size_t)bh * D_DIM * S_LEN + j0;
  #pragma unroll
  for (int l = 0; l < 2; ++l) {
    int idx = l * 256 + tid;
    int d = idx >> 3, jc = idx & 7;
    uint4 val = *(const uint4*)&T[d][jc*8];
    *(uint4*)(Ob + (size_t)d * S_LEN + jc*8) = val;
  }
}

// ---------------- histogram exclusive scan (3 stages), chunk=512 ----------------
__global__ __launch_bounds__(256) void scan1_kernel(const unsigned* __restrict__ hist,
                                                    unsigned* __restrict__ csum) {
  __shared__ unsigned sd[256];
  int c = blockIdx.x, t = threadIdx.x;
  const unsigned* p = hist + (size_t)c * 512;
  sd[t] = p[t] + p[t + 256];
  __syncthreads();
  for (int off = 128; off; off >>= 1) {
    if (t < off) sd[t] += sd[t + off];
    __syncthreads();
  }
  if (t == 0) csum[c] = sd[0];
}

__global__ __launch_bounds__(256) void scan2_kernel(unsigned* __restrict__ csum) {
  __shared__ unsigned d[256];
  int t = threadIdx.x;
  unsigned v = (t < NCHUNK) ? csum[t] : 0u;
  d[t] = v; __syncthreads();
  for (int off = 1; off < 256; off <<= 1) {
    unsigned x = (t >= off) ? d[t - off] : 0u;
    __syncthreads();
    d[t] += x;
    __syncthreads();
  }
  if (t < NCHUNK) csum[t] = d[t] - v;   // exclusive
}

// scan3: per-bin midrank -> tTab16[b] = fp16(-log(prob(midrank)))
__global__ __launch_bounds__(256) void scan3_kernel(const unsigned* __restrict__ hist,
                                                    const unsigned* __restrict__ csum,
                                                    _Float16* __restrict__ tTab16) {
  __shared__ unsigned ts[256];
  int c = blockIdx.x, t = threadIdx.x;
  const unsigned* p = hist + (size_t)c * 512 + t * 2;
  unsigned l0 = p[0], l1 = p[1];
  unsigned s = l0 + l1;
  ts[t] = s; __syncthreads();
  for (int off = 1; off < 256; off <<= 1) {
    unsigned x = (t >= off) ? ts[t - off] : 0u;
    __syncthreads();
    ts[t] += x;
    __syncthreads();
  }
  unsigned base = csum[c] + ts[t] - s;
  int idx = c * 512 + t * 2;
  float r0 = (float)base + 0.5f * ((float)l0 - 1.0f);
  tTab16[idx]     = (_Float16)(-__logf(fmaf(r0, INV_NM1, INV_N)));
  float r1 = (float)(base + l0) + 0.5f * ((float)l1 - 1.0f);
  tTab16[idx + 1] = (_Float16)(-__logf(fmaf(r1, INV_NM1, INV_N)));
}

// ------- fused map + MFMA P.V (round-12 proven, unchanged) -------
__global__ __launch_bounds__(256, 2) void pv_mfma_kernel(
    const float* __restrict__ score, const _Float16* __restrict__ Vt,
    const unsigned short* __restrict__ tTab16, float* __restrict__ out) {
  __shared__ unsigned short ldsT[NHOT];
  int tid = threadIdx.x;
  {
    const unsigned* gsrc = (const unsigned*)(tTab16 + HOT_LO);
    unsigned* ldst = (unsigned*)ldsT;
    #pragma unroll
    for (int i = 0; i < 28; ++i)
      ldst[i * 256 + tid] = gsrc[i * 256 + tid];
  }
  __syncthreads();

  int bh   = blockIdx.y;
  int wave = tid >> 6;
  int lane = tid & 63;
  int m    = lane & 15;
  int quad = lane >> 4;
  int i0   = blockIdx.x * 64 + wave * 16;
  const float*    Sb = score + ((size_t)bh * S_LEN + i0 + m) * S_LEN;
  const _Float16* Vb = Vt + (size_t)bh * D_DIM * S_LEN;
  floatx4 acc[4];
  #pragma unroll
  for (int n = 0; n < 4; ++n) acc[n] = (floatx4){0.f, 0.f, 0.f, 0.f};
  float rsum = 0.f;

  auto gather8 = [&](const float4& a, const float4& b, unsigned short* t8) {
    float sv[8] = {a.x, a.y, a.z, a.w, b.x, b.y, b.z, b.w};
    #pragma unroll
    for (int e = 0; e < 8; ++e) {
      unsigned u = __float_as_uint(sv[e]);
      unsigned av = u & 0x7fffffffu;
      unsigned bb = av >> KSHIFT;
      if (bb > NBINS - 1u) bb = NBINS - 1u;
      unsigned short tb;
      if (bb >= HOT_LO) tb = ldsT[bb - HOT_LO];
      else              tb = tTab16[bb];      // rare (~4e-4)
      if (av == 0u) tb = 0;
      t8[e] = (unsigned short)(tb ^ ((u >> 16) & 0x8000u));
    }
  };

  float4 sc0[2], sc1[2];
  unsigned short tbs[2][8];
  half8 bfs[2][4];

  sc0[0] = *(const float4*)(Sb + quad * 8);
  sc1[0] = *(const float4*)(Sb + quad * 8 + 4);
  sc0[1] = *(const float4*)(Sb + 32 + quad * 8);
  sc1[1] = *(const float4*)(Sb + 32 + quad * 8 + 4);
  #pragma unroll
  for (int n = 0; n < 4; ++n)
    bfs[0][n] = *(const half8*)(Vb + (size_t)(n * 16 + m) * S_LEN + quad * 8);
  gather8(sc0[0], sc1[0], tbs[0]);

  #pragma unroll 2
  for (int ks = 0; ks < 32; ++ks) {
    const int cur = ks & 1, nxt = cur ^ 1;
    const int kN = (ks + 1) * 32 + quad * 8;
    const int kP = (ks + 2) * 32 + quad * 8;
    #pragma unroll
    for (int n = 0; n < 4; ++n)
      bfs[nxt][n] = *(const half8*)(Vb + (size_t)(n * 16 + m) * S_LEN + kN);
    gather8(sc0[nxt], sc1[nxt], tbs[nxt]);
    sc0[cur] = *(const float4*)(Sb + kP);
    sc1[cur] = *(const float4*)(Sb + kP + 4);
    union { unsigned short u[8]; half8 h; } af;
    #pragma unroll
    for (int e = 0; e < 8; ++e) {
      unsigned short tv = tbs[cur][e];
      af.u[e] = tv;
      _Float16 th = __builtin_bit_cast(_Float16, (unsigned short)(tv & 0x7fffu));
      rsum += (float)th;
    }
    #pragma unroll
    for (int n = 0; n < 4; ++n)
      acc[n] = __builtin_amdgcn_mfma_f32_16x16x32_f16(af.h, bfs[cur][n], acc[n], 0, 0, 0);
  }

  rsum += __shfl_xor(rsum, 16);
  rsum += __shfl_xor(rsum, 32);
  float inv = 1.0f / rsum;
  #pragma unroll
  for (int r = 0; r < 4; ++r) {
    int row = quad * 4 + r;
    float invr = __shfl(inv, row);
    float* op = out + ((size_t)bh * S_LEN + i0 + row) * D_DIM + m;
    #pragma unroll
    for (int n = 0; n < 4; ++n)
      op[n * 16] = acc[n][r] * invr;
  }
}

// ---------------- launch ----------------
extern "C" void kernel_launch(void* const* d_in, const int* in_sizes, int n_in,
                              void* d_out, int out_size, void* d_ws, size_t ws_size,
                              hipStream_t stream) {
  const float* Q = (const float*)d_in[0];
  const float* K = (const float*)d_in[1];
  const float* V = (const float*)d_in[2];
  float* out = (float*)d_out;
  char* ws = (char*)d_ws;
  // Layout (max byte used 141,815,808 < round-12-proven 142,077,952):
  //   score [0, 134217728) ; hist [134217728, 134737920)
  //   P = 134737920:
  //     partial u8 P+0 .. P+6291456            (512*12288, live qkhist->hreduce)
  //     csum   P+4456448 (1016 B, scan1->scan3; inside partial range, disjoint lifetime)
  //     tTab16 P+4457472 (260096 B, scan3->pv; disjoint lifetime with partial)
  //     Vt     P+0 .. P+4194304                (vt->pv; vt runs after hreduce)
  //     qinvD P+6291456, kinvD P+6553600       (256 KB each, live norms->qkhist)
  //     qinvF P+6815744, kinvF P+6946816       (128 KB each, live norms->qkhist)
  float*         score   = (float*)(ws);
  unsigned*      hist    = (unsigned*)(ws + 134217728);
  unsigned char* partial = (unsigned char*)(ws + 134737920);
  unsigned*      csum    = (unsigned*)(ws + 139194368);
  _Float16*      tTab16  = (_Float16*)(ws + 139195392);
  _Float16*      Vt      = (_Float16*)(ws + 134737920);
  double*        qinvD   = (double*)(ws + 141029376);
  double*        kinvD   = (double*)(ws + 141291520);
  float*         qinvF   = (float*)(ws + 141553664);
  float*         kinvF   = (float*)(ws + 141684736);

  hipMemsetAsync(hist, 0, NBINS * sizeof(unsigned), stream);
  norms_kernel<<<(2 * BH * S_LEN) / 4, 256, 0, stream>>>(Q, K, qinvD, kinvD, qinvF, kinvF);
  qkhist_kernel<<<QHB, 512, 0, stream>>>(Q, K, qinvF, kinvF, qinvD, kinvD,
                                         score, hist, partial);
  hreduce_kernel<<<NHOT_H / 256, 256, 0, stream>>>(partial, hist);
  vt_kernel<<<dim3(16, BH), 256, 0, stream>>>(V, Vt);
  scan1_kernel<<<NCHUNK, 256, 0, stream>>>(hist, csum);
  scan2_kernel<<<1, 256, 0, stream>>>(csum);
  scan3_kernel<<<NCHUNK, 256, 0, stream>>>(hist, csum, tTab16);
  pv_mfma_kernel<<<dim3(16, BH), 256, 0, stream>>>(
      score, Vt, (const unsigned short*)tTab16, out);
}